// Round 7
// baseline (6498.096 us; speedup 1.0000x reference)
//
#include <hip/hip_runtime.h>
#include <stdint.h>

#define BATCH 8
#define NPTS  16384
#define BN    (BATCH * NPTS)

// ---- grid geometry: G=48 (9.7 MB ws) primary, G=40 (6.7 MB) fallback ----
template<int G> __device__ __forceinline__ float g_half() { return (G == 48) ? 5.04f : 5.12f; }
template<int G> __device__ __forceinline__ float g_w()    { return (G == 48) ? 0.21f : 0.256f; }

template<int G>
__device__ __forceinline__ int cell1d(float v) {
    const float invw = 1.0f / g_w<G>();
    int c = (int)floorf((v + g_half<G>()) * invw);
    return min(max(c, 0), G - 1);
}

// ---------------- build: count ----------------
template<int G>
__global__ __launch_bounds__(256) void bin_count_k(
    const float* __restrict__ Y, uint32_t* __restrict__ counts)
{
    const int i = blockIdx.x * 256 + threadIdx.x;   // 0..BN-1
    const int b = i >> 14, p = i & (NPTS - 1);
    const float* yp = Y + (size_t)b * NPTS * 3 + (size_t)p * 3;
    const int cx = cell1d<G>(yp[0]);
    const int cy = cell1d<G>(yp[1]);
    const int cz = cell1d<G>(yp[2]);
    const int cid = (cz * G + cy) * G + cx;
    atomicAdd(&counts[(size_t)b * (G * G * G) + cid], 1u);
}

// ---------------- build: exclusive scan (1 wave per batch) ----------------
template<int G>
__global__ __launch_bounds__(64) void scan_k(
    const uint32_t* __restrict__ counts, uint32_t* __restrict__ offsets)
{
    const int b = blockIdx.x, lane = threadIdx.x;
    const int NC = G * G * G;                 // divisible by 64 for G=48,40
    const size_t base = (size_t)b * NC;
    uint32_t run = 0;
    for (int c = lane; c < NC; c += 64) {
        const uint32_t orig = counts[base + c];
        uint32_t v = orig;
#pragma unroll
        for (int s = 1; s < 64; s <<= 1) {
            const uint32_t t = __shfl_up(v, s, 64);
            if (lane >= s) v += t;
        }
        offsets[base + c] = run + (v - orig); // exclusive prefix
        run += __shfl(v, 63, 64);
    }
}

// ---------------- build: scatter (+ exact np-order ys, pre-doubled y) -----
template<int G>
__global__ __launch_bounds__(256) void scatter_k(
    const float* __restrict__ Y, const uint32_t* __restrict__ offsets,
    uint32_t* __restrict__ cursor, float4* __restrict__ binned,
    uint32_t* __restrict__ bidx)
{
#pragma clang fp contract(off)
    const int i = blockIdx.x * 256 + threadIdx.x;
    const int b = i >> 14, p = i & (NPTS - 1);
    const float* yp = Y + (size_t)b * NPTS * 3 + (size_t)p * 3;
    const float v0 = yp[0], v1 = yp[1], v2 = yp[2];
    const float ys = (v0 * v0 + v1 * v1) + v2 * v2;      // np order
    const int cx = cell1d<G>(v0), cy = cell1d<G>(v1), cz = cell1d<G>(v2);
    const size_t cc = (size_t)b * (G * G * G) + (cz * G + cy) * G + cx;
    const uint32_t pos = offsets[cc] + atomicAdd(&cursor[cc], 1u);
    binned[(size_t)b * NPTS + pos] = make_float4(v0 + v0, v1 + v1, v2 + v2, ys);
    bidx[(size_t)b * NPTS + pos]   = (uint32_t)p;
}

// ---------------- query: expanding Chebyshev shells ----------------
// Guarantee: after visiting all cells with |cell diff| <= r, every unvisited
// point has d >= (r*w)^2 - (boundary-rounding fuzz ~1.5e-4). Terminate when
// best < (r*w)^2 - 1e-3 (margin >> fuzz). r reaching G covers the whole grid,
// so the result is the exact full min regardless of the bound.
template<int G>
__global__ __launch_bounds__(256) void query_k(
    const float* __restrict__ X, const uint32_t* __restrict__ offsets,
    const uint32_t* __restrict__ cnts, const float4* __restrict__ binned,
    const uint32_t* __restrict__ bidx,
    float* __restrict__ dist_out, float* __restrict__ idx_out)
{
#pragma clang fp contract(off)
    const int rb = blockIdx.x, b = blockIdx.z;
    const int i  = rb * 256 + threadIdx.x;

    const float* xb = X + (size_t)b * NPTS * 3;
    const float x0 = xb[i * 3 + 0];
    const float x1 = xb[i * 3 + 1];
    const float x2 = xb[i * 3 + 2];
    const float xs = (x0 * x0 + x1 * x1) + x2 * x2;      // np order

    const int cx = cell1d<G>(x0), cy = cell1d<G>(x1), cz = cell1d<G>(x2);
    const size_t cbase = (size_t)b * (G * G * G);
    const float4*   bb = binned + (size_t)b * NPTS;
    const uint32_t* ib = bidx   + (size_t)b * NPTS;

    uint64_t bestkey = ~0ull;
    bool done = false;

    for (int r = 1; r <= G; ++r) {
        if (!done) {
            // r==1: full 3x3x3 cube; r>1: shell at Chebyshev radius exactly r
            for (int dz = -r; dz <= r; ++dz)
            for (int dy = -r; dy <= r; ++dy)
            for (int dx = -r; dx <= r; ++dx) {
                if (r > 1) {
                    const int adx = dx < 0 ? -dx : dx;
                    const int ady = dy < 0 ? -dy : dy;
                    const int adz = dz < 0 ? -dz : dz;
                    if (adx != r && ady != r && adz != r) continue;   // interior done
                }
                const int ux = cx + dx, uy = cy + dy, uz = cz + dz;
                if (ux < 0 || ux >= G || uy < 0 || uy >= G ||
                    uz < 0 || uz >= G) continue;
                const size_t cid = cbase + (size_t)((uz * G + uy) * G + ux);
                const uint32_t off = offsets[cid];
                const uint32_t cnt = cnts[cid];
                for (uint32_t k = 0; k < cnt; ++k) {
                    const float4 y = bb[off + k];
                    // exact reference chain (pre-doubled y, validated R3-R6)
                    const float d = (xs - ((x0 * y.x + x1 * y.y) + x2 * y.z)) + y.w;
                    const uint32_t jj = ib[off + k];
                    uint32_t kb = __float_as_uint(d);
                    kb = (kb & 0x80000000u) ? ~kb : (kb | 0x80000000u);
                    const uint64_t key = ((uint64_t)kb << 32) | jj;
                    if (key < bestkey) bestkey = key;
                }
            }
        }
        // termination test (strict <, margin-covered -> no unvisited tie/beat)
        const float rw  = (float)r * g_w<G>();
        const float thr = rw * rw - 1e-3f;
        const uint32_t hk = (uint32_t)(bestkey >> 32);
        const uint32_t db = (hk & 0x80000000u) ? (hk ^ 0x80000000u) : ~hk;
        done = done || (__uint_as_float(db) < thr);
        if (__all(done ? 1 : 0)) break;
    }

    const uint32_t hk = (uint32_t)(bestkey >> 32);
    const uint32_t db = (hk & 0x80000000u) ? (hk ^ 0x80000000u) : ~hk;
    const size_t g = (size_t)b * NPTS + i;
    dist_out[g] = __uint_as_float(db);
    idx_out[g]  = (float)(uint32_t)(bestkey & 0xFFFFFFFFu);
}

// ---------------- host-side orchestration ----------------
template<int G>
static void run_dir(const float* Xq, const float* Ypts,
                    float* dist, float* idxf, void* d_ws, hipStream_t stream)
{
    const size_t NC8 = (size_t)G * G * G * BATCH;
    uint32_t* counts  = (uint32_t*)d_ws;               // also cursor, then cnts
    uint32_t* offsets = counts + NC8;
    float4*   binned  = (float4*)(offsets + NC8);      // 16B-aligned (NC8*8 bytes)
    uint32_t* bidx    = (uint32_t*)(binned + BN);

    hipMemsetAsync(counts, 0, NC8 * sizeof(uint32_t), stream);
    bin_count_k<G><<<BN / 256, 256, 0, stream>>>(Ypts, counts);
    scan_k<G><<<BATCH, 64, 0, stream>>>(counts, offsets);
    hipMemsetAsync(counts, 0, NC8 * sizeof(uint32_t), stream);
    scatter_k<G><<<BN / 256, 256, 0, stream>>>(Ypts, offsets, counts, binned, bidx);
    // after scatter, counts[cell] == per-cell count again
    const dim3 gq(NPTS / 256, 1, BATCH);
    query_k<G><<<gq, 256, 0, stream>>>(Xq, offsets, counts, binned, bidx,
                                       dist, idxf);
}

extern "C" void kernel_launch(void* const* d_in, const int* in_sizes, int n_in,
                              void* d_out, int out_size, void* d_ws, size_t ws_size,
                              hipStream_t stream) {
    const float* xyz1 = (const float*)d_in[0];
    const float* xyz2 = (const float*)d_in[1];
    float* out = (float*)d_out;

    float* dist1 = out;
    float* dist2 = out + BN;
    float* idx1  = out + 2 * BN;
    float* idx2  = out + 3 * BN;

    const size_t need48 = ((size_t)48 * 48 * 48 * BATCH * 8) + (size_t)BN * 20;
    if (ws_size >= need48) {            // 9.7 MB; ws >= 12 MB proven in R6
        run_dir<48>(xyz1, xyz2, dist1, idx1, d_ws, stream);
        run_dir<48>(xyz2, xyz1, dist2, idx2, d_ws, stream);
    } else {                            // 6.7 MB fallback
        run_dir<40>(xyz1, xyz2, dist1, idx1, d_ws, stream);
        run_dir<40>(xyz2, xyz1, dist2, idx2, d_ws, stream);
    }
}

// Round 8
// 776.723 us; speedup vs baseline: 8.3660x; 8.3660x over previous
//
#include <hip/hip_runtime.h>
#include <stdint.h>

#define BATCH 8
#define NPTS  16384
#define BN    (BATCH * NPTS)
#define CHPTS 512               // points staged per chunk (32 KB LDS)
#define NCH   (NPTS / CHPTS)    // 32
#define QPB   128               // queries per block = 4 waves x 2 qtiles x 16
#define MARGIN 2.0e-3f          // >= 2*delta(approx-vs-exact), see header note

typedef float f32x4 __attribute__((ext_vector_type(4)));
typedef short s16x8 __attribute__((ext_vector_type(8)));

// RNE f32 -> bf16 bits / back. Splitting h=RN(v), e=v-h is exact f32.
__device__ __forceinline__ uint16_t bfr(float x) {
    uint32_t u = __float_as_uint(x);
    return (uint16_t)((u + 0x7FFFu + ((u >> 16) & 1u)) >> 16);
}
__device__ __forceinline__ float bff(uint16_t s) {
    return __uint_as_float(((uint32_t)s) << 16);
}
__device__ __forceinline__ void split3(float v, uint16_t* a, uint16_t* b, uint16_t* c) {
    *a = bfr(v);            float f0 = bff(*a);
    *b = bfr(v - f0);       float f1 = bff(*b);
    *c = bfr((v - f0) - f1);
}
__device__ __forceinline__ uint32_t pk2(uint16_t lo, uint16_t hi) {
    return (uint32_t)lo | ((uint32_t)hi << 16);
}

// ---- prep: encode point side into 4 K-chunk planes of 8 bf16 ----
// K slots: 0-2 A:xs3*1 | 3-5 1*ys3 | per dim d: hh,hm,mh,hl,lh,mm (Y=-2y)
// layout: enc[b][chunk][plane 0..3][pt 0..511] each 16B
__global__ __launch_bounds__(256) void enc_kernel(
    const float* __restrict__ Y, uint4* __restrict__ enc)
{
#pragma clang fp contract(off)
    const int g = blockIdx.x * 256 + threadIdx.x;     // 0..BN-1
    const int b = g >> 14, p = g & (NPTS - 1);
    const float y0 = Y[(size_t)g * 3 + 0];
    const float y1 = Y[(size_t)g * 3 + 1];
    const float y2 = Y[(size_t)g * 3 + 2];
    const float ys = (y0 * y0 + y1 * y1) + y2 * y2;   // np order (approx side)
    uint16_t sa, sb, sc;  split3(ys, &sa, &sb, &sc);
    uint16_t h0, m0, l0;  split3(-2.0f * y0, &h0, &m0, &l0);
    uint16_t h1, m1, l1;  split3(-2.0f * y1, &h1, &m1, &l1);
    uint16_t h2, m2, l2;  split3(-2.0f * y2, &h2, &m2, &l2);
    const uint16_t ONEB = 0x3F80;

    const size_t base = (((size_t)b * NCH + (p >> 9)) * 4) * CHPTS + (p & 511);
    // plane0: [1,1,1,ysa,ysb,ysc,Yh0,Ym0]
    enc[base + 0 * CHPTS] = make_uint4(pk2(ONEB, ONEB), pk2(ONEB, sa), pk2(sb, sc), pk2(h0, m0));
    // plane1: [Yh0,Yl0,Yh0,Ym0,Yh1,Ym1,Yh1,Yl1]
    enc[base + 1 * CHPTS] = make_uint4(pk2(h0, l0), pk2(h0, m0), pk2(h1, m1), pk2(h1, l1));
    // plane2: [Yh1,Ym1,Yh2,Ym2,Yh2,Yl2,Yh2,Ym2]
    enc[base + 2 * CHPTS] = make_uint4(pk2(h1, m1), pk2(h2, m2), pk2(h2, l2), pk2(h2, m2));
    // plane3: zeros
    enc[base + 3 * CHPTS] = make_uint4(0, 0, 0, 0);
}

// ---- fused sweep kernel: MFMA min (m'), then MFMA candidate + exact eval ----
__global__ __launch_bounds__(256) void nn_mfma(
    const float* __restrict__ X, const float* __restrict__ Yraw,
    const uint4* __restrict__ enc,
    float* __restrict__ dist_out, float* __restrict__ idx_out)
{
#pragma clang fp contract(off)
    __shared__ uint4 lds[4 * CHPTS];               // 32 KB [plane][pt]
    __shared__ unsigned long long keys[QPB];

    const int tid  = threadIdx.x;
    const int lane = tid & 63;
    const int w    = tid >> 6;
    const int b    = blockIdx.z;
    const int qblk = blockIdx.x * QPB;
    const int qt0  = qblk + w * 32;                // wave owns 32 queries
    const int col  = lane & 15;
    const int hi   = lane >> 4;

    if (tid < QPB) keys[tid] = ~0ull;

    // ---- A-side encode (2 qtiles), lane row = col, k-chunk = hi ----
    s16x8 afr[2];
    {
        const uint16_t ONEB = 0x3F80;
#pragma unroll
        for (int t = 0; t < 2; ++t) {
            const int q = qt0 + t * 16 + col;
            const float* xp = X + ((size_t)b * NPTS + q) * 3;
            const float x0 = xp[0], x1 = xp[1], x2 = xp[2];
            const float xs = (x0 * x0 + x1 * x1) + x2 * x2;
            uint16_t sa, sb, sc;  split3(xs, &sa, &sb, &sc);
            uint16_t h0, m0, l0;  split3(x0, &h0, &m0, &l0);
            uint16_t h1, m1, l1;  split3(x1, &h1, &m1, &l1);
            uint16_t h2, m2, l2;  split3(x2, &h2, &m2, &l2);
            s16x8 a;
            if (hi == 0) {
                a[0]=sa; a[1]=sb; a[2]=sc; a[3]=ONEB; a[4]=ONEB; a[5]=ONEB; a[6]=h0; a[7]=h0;
            } else if (hi == 1) {
                a[0]=m0; a[1]=h0; a[2]=l0; a[3]=m0; a[4]=h1; a[5]=h1; a[6]=m1; a[7]=h1;
            } else if (hi == 2) {
                a[0]=l1; a[1]=m1; a[2]=h2; a[3]=h2; a[4]=m2; a[5]=h2; a[6]=l2; a[7]=m2;
            } else {
                a[0]=0; a[1]=0; a[2]=0; a[3]=0; a[4]=0; a[5]=0; a[6]=0; a[7]=0;
            }
            afr[t] = a;
        }
    }

    const size_t encbase = (size_t)b * NCH * (4 * CHPTS);
    const f32x4 zf = {0.0f, 0.0f, 0.0f, 0.0f};
    const float INF = __builtin_inff();

    // ================= sweep 1: per-query approx min =================
    f32x4 run0 = {INF, INF, INF, INF}, run1 = {INF, INF, INF, INF};
    for (int c = 0; c < NCH; ++c) {
        __syncthreads();
        {
            const uint4* src = enc + encbase + (size_t)c * (4 * CHPTS);
#pragma unroll
            for (int i = 0; i < 8; ++i) lds[i * 256 + tid] = src[i * 256 + tid];
        }
        __syncthreads();
#pragma unroll 4
        for (int tile = 0; tile < CHPTS / 16; ++tile) {
            const s16x8 bf = *(const s16x8*)&lds[hi * CHPTS + tile * 16 + col];
            const f32x4 a0 = __builtin_amdgcn_mfma_f32_16x16x32_bf16(afr[0], bf, zf, 0, 0, 0);
            const f32x4 a1 = __builtin_amdgcn_mfma_f32_16x16x32_bf16(afr[1], bf, zf, 0, 0, 0);
            run0.x = fminf(run0.x, a0.x); run0.y = fminf(run0.y, a0.y);
            run0.z = fminf(run0.z, a0.z); run0.w = fminf(run0.w, a0.w);
            run1.x = fminf(run1.x, a1.x); run1.y = fminf(run1.y, a1.y);
            run1.z = fminf(run1.z, a1.z); run1.w = fminf(run1.w, a1.w);
        }
    }
    // cross-lane min over the 16 cols (xor masks 1..8 stay in the hi-group)
#pragma unroll
    for (int m = 1; m <= 8; m <<= 1) {
        run0.x = fminf(run0.x, __shfl_xor(run0.x, m, 64));
        run0.y = fminf(run0.y, __shfl_xor(run0.y, m, 64));
        run0.z = fminf(run0.z, __shfl_xor(run0.z, m, 64));
        run0.w = fminf(run0.w, __shfl_xor(run0.w, m, 64));
        run1.x = fminf(run1.x, __shfl_xor(run1.x, m, 64));
        run1.y = fminf(run1.y, __shfl_xor(run1.y, m, 64));
        run1.z = fminf(run1.z, __shfl_xor(run1.z, m, 64));
        run1.w = fminf(run1.w, __shfl_xor(run1.w, m, 64));
    }
    f32x4 cneg0, cneg1;   // C = -(m' + MARGIN): candidate <=> acc <= 0
    cneg0.x = -(run0.x + MARGIN); cneg0.y = -(run0.y + MARGIN);
    cneg0.z = -(run0.z + MARGIN); cneg0.w = -(run0.w + MARGIN);
    cneg1.x = -(run1.x + MARGIN); cneg1.y = -(run1.y + MARGIN);
    cneg1.z = -(run1.z + MARGIN); cneg1.w = -(run1.w + MARGIN);

    // ========== sweep 2: candidates + exact first-occurrence argmin ==========
#define HITQ(av, comp, t, r) \
    if ((av).comp <= 0.0f) { \
        const int row = qt0 + (t) * 16 + hi * 4 + (r); \
        const float* xp = X + ((size_t)b * NPTS + row) * 3; \
        const float qx0 = xp[0], qx1 = xp[1], qx2 = xp[2]; \
        const float qxs = (qx0 * qx0 + qx1 * qx1) + qx2 * qx2; \
        const float* yp = Yraw + ((size_t)b * NPTS + j) * 3; \
        const float py0 = yp[0], py1 = yp[1], py2 = yp[2]; \
        const float pys = (py0 * py0 + py1 * py1) + py2 * py2; \
        const float dd = (qxs - 2.0f * ((qx0 * py0 + qx1 * py1) + qx2 * py2)) + pys; \
        uint32_t kb = __float_as_uint(dd); \
        kb = (kb & 0x80000000u) ? ~kb : (kb | 0x80000000u); \
        const unsigned long long key = ((unsigned long long)kb << 32) | (uint32_t)j; \
        atomicMin(&keys[row - qblk], key); \
    }

    for (int c = 0; c < NCH; ++c) {
        __syncthreads();
        {
            const uint4* src = enc + encbase + (size_t)c * (4 * CHPTS);
#pragma unroll
            for (int i = 0; i < 8; ++i) lds[i * 256 + tid] = src[i * 256 + tid];
        }
        __syncthreads();
#pragma unroll 2
        for (int tile = 0; tile < CHPTS / 16; ++tile) {
            const s16x8 bf = *(const s16x8*)&lds[hi * CHPTS + tile * 16 + col];
            const f32x4 a0 = __builtin_amdgcn_mfma_f32_16x16x32_bf16(afr[0], bf, cneg0, 0, 0, 0);
            const f32x4 a1 = __builtin_amdgcn_mfma_f32_16x16x32_bf16(afr[1], bf, cneg1, 0, 0, 0);
            const float mn = fminf(fminf(fminf(a0.x, a0.y), fminf(a0.z, a0.w)),
                                   fminf(fminf(a1.x, a1.y), fminf(a1.z, a1.w)));
            if (mn <= 0.0f) {                         // rare (~6% of iters)
                const int j = c * CHPTS + tile * 16 + col;
                HITQ(a0, x, 0, 0) HITQ(a0, y, 0, 1) HITQ(a0, z, 0, 2) HITQ(a0, w, 0, 3)
                HITQ(a1, x, 1, 0) HITQ(a1, y, 1, 1) HITQ(a1, z, 1, 2) HITQ(a1, w, 1, 3)
            }
        }
    }
#undef HITQ

    __syncthreads();
    if (tid < QPB) {
        const unsigned long long m = keys[tid];
        const uint32_t k32 = (uint32_t)(m >> 32);
        const uint32_t db  = (k32 & 0x80000000u) ? (k32 ^ 0x80000000u) : ~k32;
        const size_t g = (size_t)b * NPTS + qblk + tid;
        dist_out[g] = __uint_as_float(db);
        idx_out[g]  = (float)(uint32_t)(m & 0xFFFFFFFFu);
    }
}

extern "C" void kernel_launch(void* const* d_in, const int* in_sizes, int n_in,
                              void* d_out, int out_size, void* d_ws, size_t ws_size,
                              hipStream_t stream) {
    const float* xyz1 = (const float*)d_in[0];
    const float* xyz2 = (const float*)d_in[1];
    float* out = (float*)d_out;

    float* dist1 = out;
    float* dist2 = out + BN;
    float* idx1  = out + 2 * BN;
    float* idx2  = out + 3 * BN;

    uint4* enc = (uint4*)d_ws;                    // 8 MiB, reused per direction

    const dim3 gq(NPTS / QPB, 1, BATCH);          // 128 x 8 = 1024 blocks

    enc_kernel<<<BN / 256, 256, 0, stream>>>(xyz2, enc);
    nn_mfma<<<gq, 256, 0, stream>>>(xyz1, xyz2, enc, dist1, idx1);

    enc_kernel<<<BN / 256, 256, 0, stream>>>(xyz1, enc);
    nn_mfma<<<gq, 256, 0, stream>>>(xyz2, xyz1, enc, dist2, idx2);
}

// Round 10
// 632.098 us; speedup vs baseline: 10.2802x; 1.2288x over previous
//
#include <hip/hip_runtime.h>
#include <stdint.h>

#define BATCH 8
#define NPTS  16384
#define BN    (BATCH * NPTS)
#define CH    512                 // points per LDS chunk
#define NCH   (NPTS / CH)         // 32
#define QPB   128                 // 4 waves x 32 queries
#define MARGIN 1.0e-2f            // >> 2*delta(double-bf16-split approx error)

typedef float f32x16 __attribute__((ext_vector_type(16)));
typedef short s16x8  __attribute__((ext_vector_type(8)));

// RNE f32->bf16 bits and back; split2: v = a + b + eps, |eps| <= 2^-18 |v|
__device__ __forceinline__ uint16_t bfr(float x) {
    uint32_t u = __float_as_uint(x);
    return (uint16_t)((u + 0x7FFFu + ((u >> 16) & 1u)) >> 16);
}
__device__ __forceinline__ float bff(uint16_t s) {
    return __uint_as_float(((uint32_t)s) << 16);
}
__device__ __forceinline__ void split2(float v, uint16_t* a, uint16_t* b) {
    *a = bfr(v); *b = bfr(v - bff(*a));
}
__device__ __forceinline__ uint32_t pk2(uint16_t lo, uint16_t hi) {
    return (uint32_t)lo | ((uint32_t)hi << 16);
}

// ---- enc: per point, 16 bf16 B-slots = [1,1,Ya,Yb, H0,M0,H0,M0 | H1,M1,H1,M1, H2,M2,H2,M2]
// (Ya,Yb)=split2(ys), (Hd,Md)=split2(-2*yd). Layout [b][chunk][half][p] of uint4.
__global__ __launch_bounds__(256) void enc_kernel(
    const float* __restrict__ Y, uint4* __restrict__ enc)
{
#pragma clang fp contract(off)
    const int g = blockIdx.x * 256 + threadIdx.x;     // 0..BN-1
    const int b = g >> 14, p = g & (NPTS - 1);
    const float y0 = Y[(size_t)g * 3 + 0];
    const float y1 = Y[(size_t)g * 3 + 1];
    const float y2 = Y[(size_t)g * 3 + 2];
    const float ys = (y0 * y0 + y1 * y1) + y2 * y2;   // np order (approx side)
    uint16_t Ya, Yb; split2(ys, &Ya, &Yb);
    uint16_t H0, M0; split2(-2.0f * y0, &H0, &M0);
    uint16_t H1, M1; split2(-2.0f * y1, &H1, &M1);
    uint16_t H2, M2; split2(-2.0f * y2, &H2, &M2);
    const uint16_t ONE = 0x3F80;
    const int ch = p >> 9, pp = p & (CH - 1);
    const size_t base = (size_t)(b * NCH + ch) * 1024 + pp;
    enc[base]       = make_uint4(pk2(ONE, ONE), pk2(Ya, Yb), pk2(H0, M0), pk2(H0, M0));
    enc[base + 512] = make_uint4(pk2(H1, M1), pk2(H1, M1), pk2(H2, M2), pk2(H2, M2));
}

#define F16(M_) M_(0) M_(1) M_(2) M_(3) M_(4) M_(5) M_(6) M_(7) \
                M_(8) M_(9) M_(10) M_(11) M_(12) M_(13) M_(14) M_(15)

// Two-sweep exact NN with runtime-calibrated C/D layout.
__global__ __launch_bounds__(256, 4) void nn_mfma(
    const float* __restrict__ xyz1, const float* __restrict__ xyz2,
    const uint4* __restrict__ encA, const uint4* __restrict__ encB,
    float* __restrict__ out, int ndir, int dir0)
{
#pragma clang fp contract(off)
    __shared__ uint4 lds[2 * CH];                      // 16 KB
    __shared__ unsigned long long keys[QPB];

    const int tid = threadIdx.x;
    const int l   = tid & 63;
    const int wv  = tid >> 6;
    const int col = l & 31;
    const int hi  = l >> 5;

    int dir, batch, xblk;
    {
        const int g = blockIdx.x;
        if (ndir == 2) {                // bijective (dir,batch,xblk) decode
            const int s = 2 * (g & 7) + ((g >> 3) & 1);
            dir = s >> 3; batch = s & 7; xblk = g >> 4;
        } else {
            dir = dir0; batch = g & 7; xblk = g >> 3;
        }
    }

    const float* Xp = dir ? xyz2 : xyz1;
    const float* Yp = dir ? xyz1 : xyz2;
    const uint4* ep = (dir ? encB : encA) + (size_t)batch * (NCH * 1024);
    const int bofs  = batch * NPTS;
    const int qbase = xblk * QPB + wv * 32;            // batch-local

    if (tid < QPB) keys[tid] = ~0ull;

    const f32x16 zf = {0.f,0.f,0.f,0.f,0.f,0.f,0.f,0.f,
                       0.f,0.f,0.f,0.f,0.f,0.f,0.f,0.f};

    // ---- self-calibration: measure actual C/D (row,col) labels ----
    // probe1: A[k0]=row-label, B[k0]=1  -> acc[i] = row label of (lane,reg i)
    // probe2: A[k0]=1, B[k0]=col-label  -> acc[i] = col label of (lane,reg i)
    // (slot0-of-group0 on both sides: immune to any consistent K permutation)
    f32x16 rowp, colp;
    {
        s16x8 pa = {0,0,0,0,0,0,0,0}, pb = {0,0,0,0,0,0,0,0};
        if (hi == 0) { pa[0] = (short)bfr((float)col); pb[0] = (short)0x3F80; }
        rowp = __builtin_amdgcn_mfma_f32_32x32x16_bf16(pa, pb, zf, 0, 0, 0);
        s16x8 pc = {0,0,0,0,0,0,0,0}, pd = {0,0,0,0,0,0,0,0};
        if (hi == 0) { pc[0] = (short)0x3F80; pd[0] = (short)bfr((float)col); }
        colp = __builtin_amdgcn_mfma_f32_32x32x16_bf16(pc, pd, zf, 0, 0, 0);
    }

    // ---- A fragment: query qbase+col, k-slots of group hi ----
    s16x8 afr;
    {
        const float* xp = Xp + (size_t)(bofs + qbase + col) * 3;
        const float x0 = xp[0], x1 = xp[1], x2 = xp[2];
        const float xs = (x0 * x0 + x1 * x1) + x2 * x2;
        uint16_t Xa, Xb; split2(xs, &Xa, &Xb);
        uint16_t h0, m0; split2(x0, &h0, &m0);
        uint16_t h1, m1; split2(x1, &h1, &m1);
        uint16_t h2, m2; split2(x2, &h2, &m2);
        const uint16_t ONE = 0x3F80;
        if (hi == 0) {
            afr[0]=(short)Xa; afr[1]=(short)Xb; afr[2]=(short)ONE; afr[3]=(short)ONE;
            afr[4]=(short)h0; afr[5]=(short)h0; afr[6]=(short)m0;  afr[7]=(short)m0;
        } else {
            afr[0]=(short)h1; afr[1]=(short)h1; afr[2]=(short)m1;  afr[3]=(short)m1;
            afr[4]=(short)h2; afr[5]=(short)h2; afr[6]=(short)m2;  afr[7]=(short)m2;
        }
    }

    const int ldsb = hi * CH + col;                    // uint4 index

    // ================= sweep 1: per-query approx min =================
    f32x16 run;
#define RINIT(i) run[i] = __builtin_inff();
    F16(RINIT)
#undef RINIT
    for (int c = 0; c < NCH; ++c) {
        __syncthreads();
        {
            const uint4* src = ep + (size_t)c * 1024;
#pragma unroll
            for (int i = 0; i < 4; ++i) lds[i * 256 + tid] = src[i * 256 + tid];
        }
        __syncthreads();
#pragma unroll
        for (int t = 0; t < CH / 32; ++t) {
            const s16x8 bf = *(const s16x8*)&lds[ldsb + t * 32];
            const f32x16 acc = __builtin_amdgcn_mfma_f32_32x32x16_bf16(afr, bf, zf, 0, 0, 0);
#define RMIN(i) run[i] = fminf(run[i], acc[i]);
            F16(RMIN)
#undef RMIN
        }
    }
    // cross-lane min over the 32 cols (masks 1..16 stay within the hi-half)
#pragma unroll
    for (int mk = 1; mk <= 16; mk <<= 1) {
#define XMIN(i) run[i] = fminf(run[i], __shfl_xor(run[i], mk, 64));
        F16(XMIN)
#undef XMIN
    }
    f32x16 cneg;                  // C = -(m'+MARGIN): candidate <=> acc <= 0
#define CNEG(i) cneg[i] = -(run[i] + MARGIN);
    F16(CNEG)
#undef CNEG

    // ====== sweep 2: candidates + exact first-occurrence argmin ======
    for (int c = 0; c < NCH; ++c) {
        __syncthreads();
        {
            const uint4* src = ep + (size_t)c * 1024;
#pragma unroll
            for (int i = 0; i < 4; ++i) lds[i * 256 + tid] = src[i * 256 + tid];
        }
        __syncthreads();
#pragma unroll
        for (int t = 0; t < CH / 32; ++t) {
            const s16x8 bf = *(const s16x8*)&lds[ldsb + t * 32];
            const f32x16 acc = __builtin_amdgcn_mfma_f32_32x32x16_bf16(afr, bf, cneg, 0, 0, 0);
            const float m0_ = fminf(fminf(fminf(acc[0],  acc[1]),  fminf(acc[2],  acc[3])),
                                    fminf(fminf(acc[4],  acc[5]),  fminf(acc[6],  acc[7])));
            const float m1_ = fminf(fminf(fminf(acc[8],  acc[9]),  fminf(acc[10], acc[11])),
                                    fminf(fminf(acc[12], acc[13]), fminf(acc[14], acc[15])));
            if (fminf(m0_, m1_) <= 0.0f) {             // rare
#define HITR(r) if (acc[r] <= 0.0f) { \
                    const int rl = (int)rowp[r]; \
                    const int jc = c * CH + t * 32 + (int)colp[r]; \
                    const float* xq = Xp + (size_t)(bofs + qbase + rl) * 3; \
                    const float qx0 = xq[0], qx1 = xq[1], qx2 = xq[2]; \
                    const float qxs = (qx0 * qx0 + qx1 * qx1) + qx2 * qx2; \
                    const float* yq = Yp + (size_t)(bofs + jc) * 3; \
                    const float py0 = yq[0], py1 = yq[1], py2 = yq[2]; \
                    const float pys = (py0 * py0 + py1 * py1) + py2 * py2; \
                    const float dd = (qxs - 2.0f * ((qx0 * py0 + qx1 * py1) + qx2 * py2)) + pys; \
                    uint32_t kb = __float_as_uint(dd); \
                    kb = (kb & 0x80000000u) ? ~kb : (kb | 0x80000000u); \
                    atomicMin(&keys[wv * 32 + rl], \
                              ((unsigned long long)kb << 32) | (uint32_t)jc); }
                F16(HITR)
#undef HITR
            }
        }
    }

    __syncthreads();
    if (tid < QPB) {
        const unsigned long long m = keys[tid];
        const uint32_t k32 = (uint32_t)(m >> 32);
        const uint32_t db  = (k32 & 0x80000000u) ? (k32 ^ 0x80000000u) : ~k32;
        const size_t gq = (size_t)bofs + (size_t)xblk * QPB + tid;
        float* distp = out + (size_t)dir * BN;
        float* idxp  = out + (size_t)(2 + dir) * BN;
        distp[gq] = __uint_as_float(db);
        idxp[gq]  = (float)(uint32_t)(m & 0xFFFFFFFFu);
    }
}

extern "C" void kernel_launch(void* const* d_in, const int* in_sizes, int n_in,
                              void* d_out, int out_size, void* d_ws, size_t ws_size,
                              hipStream_t stream) {
    const float* xyz1 = (const float*)d_in[0];
    const float* xyz2 = (const float*)d_in[1];
    float* out = (float*)d_out;

    uint4* encA = (uint4*)d_ws;                   // 4 MiB
    uint4* encB = encA + (size_t)BN * 2;          // 4 MiB

    if (ws_size >= (size_t)8 * 1024 * 1024) {
        enc_kernel<<<BN / 256, 256, 0, stream>>>(xyz2, encA);
        enc_kernel<<<BN / 256, 256, 0, stream>>>(xyz1, encB);
        nn_mfma<<<2048, 256, 0, stream>>>(xyz1, xyz2, encA, encB, out, 2, 0);
    } else {                                      // sequential, reuse encA
        enc_kernel<<<BN / 256, 256, 0, stream>>>(xyz2, encA);
        nn_mfma<<<1024, 256, 0, stream>>>(xyz1, xyz2, encA, encA, out, 1, 0);
        enc_kernel<<<BN / 256, 256, 0, stream>>>(xyz1, encA);
        nn_mfma<<<1024, 256, 0, stream>>>(xyz1, xyz2, encA, encA, out, 1, 1);
    }
}